// Round 8
// baseline (468.331 us; speedup 1.0000x reference)
//
#include <hip/hip_runtime.h>

#define L_SEQ 2048
#define BATCH 16
#define DDIM  1024
#define MDIM  (L_SEQ * BATCH)   // 32768
#define NDIM  (3 * DDIM)        // 3072
#define KDIM  DDIM              // 1024
#define CH    (BATCH * DDIM)    // 16384
#define NSEG  32
#define SEGL  64                // L_SEQ / NSEG

typedef __attribute__((ext_vector_type(8))) short short8;
typedef __attribute__((ext_vector_type(4))) float f32x4;
typedef __attribute__((ext_vector_type(16))) float f32x16;

static __device__ __forceinline__ unsigned short f2bf(float f) {
  unsigned int u = __builtin_bit_cast(unsigned int, f);
  unsigned int lsb = (u >> 16) & 1u;
  u += 0x7fffu + lsb;
  return (unsigned short)(u >> 16);
}
static __device__ __forceinline__ float bf2f(unsigned short s) {
  unsigned int u = ((unsigned int)s) << 16;
  return __builtin_bit_cast(float, u);
}

static __device__ __forceinline__ void gll16(const void* g, void* l) {
  __builtin_amdgcn_global_load_lds(
      (const __attribute__((address_space(1))) unsigned int*)g,
      (__attribute__((address_space(3))) unsigned int*)l, 16, 0, 0);
}

// ---- converters ----------------------------------------------------------

__global__ void k_convert_x(const float4* __restrict__ x, ushort4* __restrict__ xb, int n4) {
  int i = blockIdx.x * blockDim.x + threadIdx.x;
  int stride = gridDim.x * blockDim.x;
  for (; i < n4; i += stride) {
    float4 v = x[i];
    ushort4 o;
    o.x = f2bf(v.x); o.y = f2bf(v.y); o.z = f2bf(v.z); o.w = f2bf(v.w);
    xb[i] = o;
  }
}

// Wb[n][k] = bf16( W[k][colmap(n)] ): regions {xt, f, r} -> contiguous col ranges
__global__ void k_convert_w(const float* __restrict__ w, unsigned short* __restrict__ wb) {
  int gid = blockIdx.x * 256 + threadIdx.x;   // 3072*1024 total
  int k = gid & (KDIM - 1);
  int n = gid >> 10;
  int col = (n < DDIM) ? 3 * n : (n < 2 * DDIM) ? 3 * (n - DDIM) + 1 : 3 * (n - 2 * DDIM) + 2;
  wb[gid] = f2bf(w[(size_t)k * NDIM + col]);
}

// ---- GEMM: 256x256, BK=32, 8 waves, 32x32x16 MFMA, 4-buf 2-deep staging --
// LDS: 4 buffers x 32KB { A 256x64B | B 256x64B }; 16B-slot permutation
// slot^((row>>1)&3) on both stage-source and read (proven 0-conflict).
// R7 post-mortem: MfmaUtil invariant at ~35% across 6 schedules with hidden
// ~33% VALUBusy -> per-MFMA-instruction overhead hypothesis. This kernel
// halves MFMA instruction count at constant FLOPs via the 32x32x16 shape.

#define MFMA32(ACC, A, B) \
  ACC = __builtin_amdgcn_mfma_f32_32x32x16_bf16(A, B, ACC, 0, 0, 0);

// One BK=32 tile. T = tile index; stages tile T+2 into buffer (T+2)&3.
#define TILE32(T) do {                                                        \
  const char* bufC = LDSc + ((T) & 3) * 32768;                                \
  char*       bufS = LDSc + (((T) + 2) & 3) * 32768;                          \
  const int kb = (((T) + 2) & 31) * 64;                                       \
  gll16(srcA0 + kb, bufS + dstOff);                                           \
  gll16(srcA1 + kb, bufS + 8192 + dstOff);                                    \
  gll16(srcB0 + kb, bufS + 16384 + dstOff);                                   \
  gll16(srcB1 + kb, bufS + 24576 + dstOff);                                   \
  __builtin_amdgcn_sched_barrier(0);                                          \
  fa0 = *(const short8*)(bufC + aA00);                                        \
  fa1 = *(const short8*)(bufC + aA10);                                        \
  fa2 = *(const short8*)(bufC + aA20);                                        \
  fa3 = *(const short8*)(bufC + aA30);                                        \
  fb0 = *(const short8*)(bufC + bA00);                                        \
  fb1 = *(const short8*)(bufC + bA10);                                        \
  ga0 = *(const short8*)(bufC + aA01);                                        \
  ga1 = *(const short8*)(bufC + aA11);                                        \
  ga2 = *(const short8*)(bufC + aA21);                                        \
  ga3 = *(const short8*)(bufC + aA31);                                        \
  gb0 = *(const short8*)(bufC + bA01);                                        \
  gb1 = *(const short8*)(bufC + bA11);                                        \
  __builtin_amdgcn_s_setprio(1);                                              \
  MFMA32(acc[0][0], fa0, fb0) MFMA32(acc[0][1], fa0, fb1)                     \
  MFMA32(acc[1][0], fa1, fb0) MFMA32(acc[1][1], fa1, fb1)                     \
  MFMA32(acc[2][0], fa2, fb0) MFMA32(acc[2][1], fa2, fb1)                     \
  MFMA32(acc[3][0], fa3, fb0) MFMA32(acc[3][1], fa3, fb1)                     \
  MFMA32(acc[0][0], ga0, gb0) MFMA32(acc[0][1], ga0, gb1)                     \
  MFMA32(acc[1][0], ga1, gb0) MFMA32(acc[1][1], ga1, gb1)                     \
  MFMA32(acc[2][0], ga2, gb0) MFMA32(acc[2][1], ga2, gb1)                     \
  MFMA32(acc[3][0], ga3, gb0) MFMA32(acc[3][1], ga3, gb1)                     \
  __builtin_amdgcn_s_setprio(0);                                              \
  asm volatile("s_waitcnt vmcnt(4)" ::: "memory");                            \
  __builtin_amdgcn_s_barrier();                                               \
} while (0)

__global__ __launch_bounds__(512, 2) void k_gemm256(
    const unsigned short* __restrict__ xb,   // [M][K] bf16
    const unsigned short* __restrict__ wb,   // [N][K] bf16
    const float* __restrict__ bias,          // [2d]
    unsigned short* __restrict__ xtb,        // [M][d] bf16
    unsigned short* __restrict__ fbuf,       // [M][d] bf16
    unsigned short* __restrict__ rbuf) {     // [M][d] bf16
  __shared__ char LDS[131072];
  char* LDSc = LDS;

  const int tid  = threadIdx.x;
  const int lane = tid & 63;
  const int wid  = tid >> 6;
  const int wr   = wid >> 2;     // 0..1  (128-row half)
  const int wc   = wid & 3;      // 0..3  (64-col quarter)

  // XCD-aware bijective swizzle: 1536 = 8 * 192
  int bid = blockIdx.x;
  int wg = (bid & 7) * 192 + (bid >> 3);
  int mt = wg / 12;
  int nt = wg - mt * 12;
  const int rowBase = mt * 256;
  const int colBase = nt * 256;

  // 32x32x16 fragment read addresses (12, loop-invariant).
  // A lane l: row = l&31 within 32-row frag; k-group = l>>5; kstep ks adds 2 slots.
  const int l31 = lane & 31;
  const int lh  = lane >> 5;
  int aA00, aA10, aA20, aA30, aA01, aA11, aA21, aA31;
  int bA00, bA10, bA01, bA11;
  {
    int r0 = wr * 128 + 0 * 32 + l31;
    int r1 = wr * 128 + 1 * 32 + l31;
    int r2 = wr * 128 + 2 * 32 + l31;
    int r3 = wr * 128 + 3 * 32 + l31;
    aA00 = r0 * 64 + (((lh + 0) ^ ((r0 >> 1) & 3)) << 4);
    aA10 = r1 * 64 + (((lh + 0) ^ ((r1 >> 1) & 3)) << 4);
    aA20 = r2 * 64 + (((lh + 0) ^ ((r2 >> 1) & 3)) << 4);
    aA30 = r3 * 64 + (((lh + 0) ^ ((r3 >> 1) & 3)) << 4);
    aA01 = r0 * 64 + (((lh + 2) ^ ((r0 >> 1) & 3)) << 4);
    aA11 = r1 * 64 + (((lh + 2) ^ ((r1 >> 1) & 3)) << 4);
    aA21 = r2 * 64 + (((lh + 2) ^ ((r2 >> 1) & 3)) << 4);
    aA31 = r3 * 64 + (((lh + 2) ^ ((r3 >> 1) & 3)) << 4);
    int c0 = wc * 64 + 0 * 32 + l31;
    int c1 = wc * 64 + 1 * 32 + l31;
    bA00 = 16384 + c0 * 64 + (((lh + 0) ^ ((c0 >> 1) & 3)) << 4);
    bA10 = 16384 + c1 * 64 + (((lh + 0) ^ ((c1 >> 1) & 3)) << 4);
    bA01 = 16384 + c0 * 64 + (((lh + 2) ^ ((c0 >> 1) & 3)) << 4);
    bA11 = 16384 + c1 * 64 + (((lh + 2) ^ ((c1 >> 1) & 3)) << 4);
  }

  // staging source bases (inverse permutation on global source, linear LDS dest)
  const int p0i = tid, p1i = 512 + tid;
  const int r0s = p0i >> 2, r1s = p1i >> 2;
  const int s0 = (p0i & 3) ^ ((r0s >> 1) & 3);
  const int s1 = (p1i & 3) ^ ((r1s >> 1) & 3);
  const char* srcA0 = (const char*)xb + (size_t)(rowBase + r0s) * 2048 + s0 * 16;
  const char* srcA1 = (const char*)xb + (size_t)(rowBase + r1s) * 2048 + s1 * 16;
  const char* srcB0 = (const char*)wb + (size_t)(colBase + r0s) * 2048 + s0 * 16;
  const char* srcB1 = (const char*)wb + (size_t)(colBase + r1s) * 2048 + s1 * 16;
  const int dstOff = wid * 1024;

  f32x16 acc[4][2];
#pragma unroll
  for (int ii = 0; ii < 4; ++ii)
#pragma unroll
    for (int jj = 0; jj < 2; ++jj)
#pragma unroll
      for (int e = 0; e < 16; ++e)
        acc[ii][jj][e] = 0.f;

  // prologue: stage tiles 0 and 1
  gll16(srcA0, LDSc + dstOff);
  gll16(srcA1, LDSc + 8192 + dstOff);
  gll16(srcB0, LDSc + 16384 + dstOff);
  gll16(srcB1, LDSc + 24576 + dstOff);
  gll16(srcA0 + 64, LDSc + 32768 + dstOff);
  gll16(srcA1 + 64, LDSc + 40960 + dstOff);
  gll16(srcB0 + 64, LDSc + 49152 + dstOff);
  gll16(srcB1 + 64, LDSc + 57344 + dstOff);
  asm volatile("s_waitcnt vmcnt(4)" ::: "memory");
  __builtin_amdgcn_s_barrier();

  short8 fa0, fa1, fa2, fa3, fb0, fb1;   // kstep 0
  short8 ga0, ga1, ga2, ga3, gb0, gb1;   // kstep 1

  for (int i = 0; i < 8; ++i) {
    TILE32(4 * i);
    TILE32(4 * i + 1);
    TILE32(4 * i + 2);
    TILE32(4 * i + 3);
  }
  asm volatile("s_waitcnt vmcnt(0)" ::: "memory");

  // epilogue: 32x32 C layout: row=(j&3)+8*(j>>2)+4*lh, col=l31
  const int region = colBase >> 10;
#pragma unroll
  for (int m = 0; m < 4; ++m) {
#pragma unroll
    for (int n = 0; n < 2; ++n) {
      f32x16 v = acc[m][n];
      int gcol = colBase + wc * 64 + n * 32 + l31;
      int growb = rowBase + wr * 128 + m * 32 + 4 * lh;
      if (region == 0) {
#pragma unroll
        for (int j = 0; j < 16; ++j) {
          int rr = (j & 3) + 8 * (j >> 2);
          xtb[(size_t)(growb + rr) * DDIM + gcol] = f2bf(v[j]);
        }
      } else {
        float bv = bias[gcol - DDIM];
        unsigned short* dst = (region == 1) ? fbuf : rbuf;
        int lcol = gcol - (region << 10);
#pragma unroll
        for (int j = 0; j < 16; ++j) {
          int rr = (j & 3) + 8 * (j >> 2);
          float sg = 1.0f / (1.0f + __expf(-(v[j] + bv)));
          dst[(size_t)(growb + rr) * DDIM + lcol] = f2bf(sg);
        }
      }
    }
  }
}

// ---- segmented scan ------------------------------------------------------
// pass 1: per (segment, 4 channel-pairs) affine state a = prod f, b = scan from 0
// 8 channels/thread, uint4 (16B) loads per stream (G13 vectorization)

__global__ __launch_bounds__(256) void k_scan1(
    const unsigned short* __restrict__ fbuf,
    const unsigned short* __restrict__ xtb,
    float4* __restrict__ AB) {
  int idx = blockIdx.x * 256 + threadIdx.x;       // 0..2047
  int seg = blockIdx.y;
  int pp = idx * 4;                                // first channel-pair of 4
  size_t base = (size_t)seg * SEGL * CH + (size_t)pp * 2;
  const uint4* fp = (const uint4*)(fbuf + base);
  const uint4* xp = (const uint4*)(xtb + base);
  float a[8], b[8];
#pragma unroll
  for (int e = 0; e < 8; ++e) { a[e] = 1.f; b[e] = 0.f; }
#pragma unroll 4
  for (int s = 0; s < SEGL; ++s) {
    uint4 fv = fp[(size_t)s * (CH / 8)];
    uint4 xv = xp[(size_t)s * (CH / 8)];
    unsigned int fw[4] = {fv.x, fv.y, fv.z, fv.w};
    unsigned int xw[4] = {xv.x, xv.y, xv.z, xv.w};
#pragma unroll
    for (int q = 0; q < 4; ++q) {
      float f0 = bf2f((unsigned short)fw[q]), f1 = bf2f((unsigned short)(fw[q] >> 16));
      float x0 = bf2f((unsigned short)xw[q]), x1 = bf2f((unsigned short)(xw[q] >> 16));
      b[2 * q]     = (b[2 * q] - x0) * f0 + x0;      a[2 * q]     *= f0;
      b[2 * q + 1] = (b[2 * q + 1] - x1) * f1 + x1;  a[2 * q + 1] *= f1;
    }
  }
#pragma unroll
  for (int q = 0; q < 4; ++q)
    AB[(size_t)seg * (CH / 2) + pp + q] = (float4){a[2 * q], b[2 * q], a[2 * q + 1], b[2 * q + 1]};
}

// pass 2: scan 32 segment states per channel; emit per-segment c_in and c_last

__global__ __launch_bounds__(256) void k_scan2(
    const float* __restrict__ c0,
    const float4* __restrict__ AB,
    float* __restrict__ Cin,
    float* __restrict__ clast) {
  int chp = blockIdx.x * 256 + threadIdx.x;       // 0..8191
  float2 cc = ((const float2*)c0)[chp];
  float ca = cc.x, cb = cc.y;
#pragma unroll
  for (int s = 0; s < NSEG; ++s) {
    ((float2*)Cin)[(size_t)s * (CH / 2) + chp] = (float2){ca, cb};
    float4 ab = AB[(size_t)s * (CH / 2) + chp];
    ca = ca * ab.x + ab.y;
    cb = cb * ab.z + ab.w;
  }
  ((float2*)clast)[chp] = (float2){ca, cb};
}

// pass 3: recompute c within segment from c_in; emit h. 8 channels/thread.

__global__ __launch_bounds__(256) void k_scan3(
    const float* __restrict__ x,
    const unsigned short* __restrict__ fbuf,
    const unsigned short* __restrict__ xtb,
    const unsigned short* __restrict__ rbuf,
    const float* __restrict__ Cin,
    float* __restrict__ h) {
  int idx = blockIdx.x * 256 + threadIdx.x;       // 0..2047
  int seg = blockIdx.y;
  int pp = idx * 4;
  float4 ci0 = *(const float4*)(Cin + ((size_t)seg * (CH / 2) + pp) * 2);
  float4 ci1 = *(const float4*)(Cin + ((size_t)seg * (CH / 2) + pp) * 2 + 4);
  float c[8] = {ci0.x, ci0.y, ci0.z, ci0.w, ci1.x, ci1.y, ci1.z, ci1.w};
  size_t base = (size_t)seg * SEGL * CH + (size_t)pp * 2;
  const uint4* fp = (const uint4*)(fbuf + base);
  const uint4* tp = (const uint4*)(xtb + base);
  const uint4* rp = (const uint4*)(rbuf + base);
  const float4* xp = (const float4*)(x + base);
  float4* hp = (float4*)(h + base);
#pragma unroll 2
  for (int s = 0; s < SEGL; ++s) {
    uint4 fv = fp[(size_t)s * (CH / 8)];
    uint4 tv = tp[(size_t)s * (CH / 8)];
    uint4 rv = rp[(size_t)s * (CH / 8)];
    float4 xv0 = xp[(size_t)s * (CH / 4)];
    float4 xv1 = xp[(size_t)s * (CH / 4) + 1];
    unsigned int fw[4] = {fv.x, fv.y, fv.z, fv.w};
    unsigned int tw[4] = {tv.x, tv.y, tv.z, tv.w};
    unsigned int rw[4] = {rv.x, rv.y, rv.z, rv.w};
    float xs[8] = {xv0.x, xv0.y, xv0.z, xv0.w, xv1.x, xv1.y, xv1.z, xv1.w};
    float hs[8];
#pragma unroll
    for (int q = 0; q < 4; ++q) {
      float f0 = bf2f((unsigned short)fw[q]), f1 = bf2f((unsigned short)(fw[q] >> 16));
      float t0 = bf2f((unsigned short)tw[q]), t1 = bf2f((unsigned short)(tw[q] >> 16));
      float r0 = bf2f((unsigned short)rw[q]), r1 = bf2f((unsigned short)(rw[q] >> 16));
      int e0 = 2 * q, e1 = 2 * q + 1;
      c[e0] = (c[e0] - t0) * f0 + t0;
      c[e1] = (c[e1] - t1) * f1 + t1;
      float q0 = __expf(-2.f * fabsf(c[e0]));
      float q1 = __expf(-2.f * fabsf(c[e1]));
      float g0 = copysignf((1.f - q0) / (1.f + q0), c[e0]);
      float g1 = copysignf((1.f - q1) / (1.f + q1), c[e1]);
      hs[e0] = (g0 - xs[e0]) * r0 + xs[e0];
      hs[e1] = (g1 - xs[e1]) * r1 + xs[e1];
    }
    hp[(size_t)s * (CH / 4)]     = (float4){hs[0], hs[1], hs[2], hs[3]};
    hp[(size_t)s * (CH / 4) + 1] = (float4){hs[4], hs[5], hs[6], hs[7]};
  }
}

// ---- launch --------------------------------------------------------------

extern "C" void kernel_launch(void* const* d_in, const int* in_sizes, int n_in,
                              void* d_out, int out_size, void* d_ws, size_t ws_size,
                              hipStream_t stream) {
  const float* x    = (const float*)d_in[0];
  const float* w    = (const float*)d_in[1];
  const float* bias = (const float*)d_in[2];
  const float* c0   = (const float*)d_in[3];
  float* out = (float*)d_out;
  char* ws = (char*)d_ws;

  // ws layout (207.6 MB total):
  //   [0, 6.29MB): wb (GEMM weights)  -- after GEMM, reused as AB (4MB) + Cin (2MB)
  unsigned short* wb   = (unsigned short*)(ws);
  float4*         AB   = (float4*)(ws);
  float*          Cin  = (float*)(ws + 4194304);
  unsigned short* xtb  = (unsigned short*)(ws + 6291456);
  unsigned short* fbuf = (unsigned short*)(ws + 73400320);
  unsigned short* rbuf = (unsigned short*)(ws + 140509184);
  // xb (bf16 x, 64MB) lives in d_out's h region (dead until pass 3 rewrites it)
  unsigned short* xb = (unsigned short*)d_out;

  k_convert_x<<<2048, 256, 0, stream>>>((const float4*)x, (ushort4*)xb, MDIM * KDIM / 4);
  k_convert_w<<<(NDIM * KDIM) / 256, 256, 0, stream>>>(w, wb);

  k_gemm256<<<1536, 512, 0, stream>>>(xb, wb, bias, xtb, fbuf, rbuf);

  k_scan1<<<dim3(8, NSEG), 256, 0, stream>>>(fbuf, xtb, AB);
  k_scan2<<<32, 256, 0, stream>>>(c0, AB, Cin, out + (size_t)L_SEQ * CH);
  k_scan3<<<dim3(8, NSEG), 256, 0, stream>>>(x, fbuf, xtb, rbuf, Cin, out);
}